// Round 9
// baseline (1514.889 us; speedup 1.0000x reference)
//
#include <hip/hip_runtime.h>
#include <math.h>

#define NN 64
#define LDW 68      // padded LDS stride (float4-aligned)
#define LCH 32      // mean-scan chunk length
#define N1CAP 144   // smoother-cov tail length (closed-form, parallel)
#define N0MAX 144   // forward Riccati cap
#define EPS_HARD 1e-5f
#define EPS_GATE 5e-2f
#define STALL_WIN 5
#define STALL_IMP 0.75f

struct KP {
  const float *Y, *A, *b, *Q, *H, *c, *R, *pm0, *P0;
  float *out_mean, *out_cov, *out_ll;
  int *meta; float *metaF;
  float *fm;
  float *AT, *HT, *HA, *Hb;
  float *Fss, *Kss, *Sinvss, *Css, *CsTss, *pPss, *sPss, *Fpow, *Cpow32, *Cpow31, *uss;
  float *Pw2, *Pw4, *Pw8, *Pw16, *Pw64, *Pw128;
  float *FpwHi, *CpwHi;                   // F^(64..2048) [6], C^(256..2048) [4]
  float *Dmss, *dvnss;                    // I - Css*A ; -Css*b (fused backward scan)
  float *scanF0, *scanF1, *scanB0, *scanB1;           // chunk-carry scan buffers
  float *ld_pref, *u_pref;
  double *llbuf;
  float *E0g;
  float *EA, *EC, *EJ, *EL;
  float *astat, *dstat;
  float *scM0, *scM1, *scG0, *scG1;       // (cap+32) slots each
  float *fP, *pP, *Kp, *Sinvp, *Fp, *Cp, *CsTp, *Dmp, *dvnp;
  int N0cap, T, NC;
};

union F4 { float4 v; float f[4]; };

// ---------- helpers (blockDim.x == 256 unless noted) ----------

__device__ __forceinline__ void g2l(float* W, const float* G) {
  for (int e = threadIdx.x*4; e < 4096; e += 1024) {
    float4 v = *(const float4*)(G + e);
    *(float4*)(W + (e>>6)*LDW + (e&63)) = v;
  }
  __syncthreads();
}
__device__ __forceinline__ void l2g(float* G, const float* W) {
  for (int e = threadIdx.x*4; e < 4096; e += 1024)
    *(float4*)(G + e) = *(const float4*)(W + (e>>6)*LDW + (e&63));
  __syncthreads();
}
__device__ __forceinline__ void l2g2(float* G1, const float* Wa,
                                     float* G2, const float* Wb) {
  for (int e = threadIdx.x*4; e < 4096; e += 1024) {
    int base = (e>>6)*LDW + (e&63);
    *(float4*)(G1 + e) = *(const float4*)(Wa + base);
    *(float4*)(G2 + e) = *(const float4*)(Wb + base);
  }
  __syncthreads();
}
__device__ __forceinline__ void l2g3(float* G1, const float* Wa,
                                     float* G2, const float* Wb,
                                     float* G3, const float* Wc) {
  for (int e = threadIdx.x*4; e < 4096; e += 1024) {
    int base = (e>>6)*LDW + (e&63);
    *(float4*)(G1 + e) = *(const float4*)(Wa + base);
    *(float4*)(G2 + e) = *(const float4*)(Wb + base);
    *(float4*)(G3 + e) = *(const float4*)(Wc + base);
  }
  __syncthreads();
}
__device__ __forceinline__ void l2g_T(float* G, const float* W) {
  for (int e = threadIdx.x; e < 4096; e += 256)
    G[e] = W[(e&63)*LDW + (e>>6)];
  __syncthreads();
}
__device__ __forceinline__ void copyW(float* D, const float* S) {
  for (int e = threadIdx.x*4; e < 4096; e += 1024) {
    int base = (e>>6)*LDW + (e&63);
    *(float4*)(D + base) = *(const float4*)(S + base);
  }
  __syncthreads();
}
__device__ __forceinline__ void set_id(float* W) {
  for (int e = threadIdx.x; e < 4096; e += 256)
    W[(e>>6)*LDW + (e&63)] = ((e>>6) == (e&63)) ? 1.f : 0.f;
  __syncthreads();
}
// G = I - W (LDS -> global)
__device__ __forceinline__ void store_id_sub(float* G, const float* W) {
  for (int e = threadIdx.x; e < 4096; e += 256)
    G[e] = (((e>>6) == (e&63)) ? 1.f : 0.f) - W[(e>>6)*LDW + (e&63)];
  __syncthreads();
}
// G_dst = G_src - W
__device__ __forceinline__ void rsub_store(float* Gd, const float* Gs, const float* W) {
  for (int e = threadIdx.x*4; e < 4096; e += 1024) {
    int base = (e>>6)*LDW + (e&63);
    F4 a, g; a.v = *(const float4*)(W + base); g.v = *(const float4*)(Gs + e);
    F4 o; o.f[0]=g.f[0]-a.f[0]; o.f[1]=g.f[1]-a.f[1]; o.f[2]=g.f[2]-a.f[2]; o.f[3]=g.f[3]-a.f[3];
    *(float4*)(Gd + e) = o.v;
  }
  __syncthreads();
}

__device__ __forceinline__ void redpair(float& ma, float& md, float* red) {
  #pragma unroll
  for (int off = 32; off; off >>= 1) {
    ma = fmaxf(ma, __shfl_xor(ma, off, 64));
    md = fmaxf(md, __shfl_xor(md, off, 64));
  }
  const int w = threadIdx.x >> 6;
  if ((threadIdx.x & 63) == 0) { red[w] = ma; red[4 + w] = md; }
  __syncthreads();
  ma = fmaxf(fmaxf(red[0], red[1]), fmaxf(red[2], red[3]));
  md = fmaxf(fmaxf(red[4], red[5]), fmaxf(red[6], red[7]));
  __syncthreads();
}

// D(stride LDD) = [ADD +/-] op(A)*op(B).  MODE 3: D = A*B + I.
template<int TRANSA, int TRANSB, int MODE, int LDD>
__device__ __forceinline__ void mm(float* __restrict__ D,
    const float* __restrict__ A, int lda,
    const float* __restrict__ B, int ldb,
    const float* __restrict__ ADD, int ldadd)
{
  const int tid = threadIdx.x;
  const int i0 = (tid >> 4) << 2, j0 = (tid & 15) << 2;
  float acc[4][4] = {};
  for (int k0 = 0; k0 < NN; k0 += 4) {
    F4 av[4], bv[4];
    #pragma unroll
    for (int u = 0; u < 4; ++u) {
      bv[u].v = TRANSB ? *(const float4*)(B + (j0+u)*ldb + k0)
                       : *(const float4*)(B + (k0+u)*ldb + j0);
      av[u].v = TRANSA ? *(const float4*)(A + (k0+u)*lda + i0)
                       : *(const float4*)(A + (i0+u)*lda + k0);
    }
    #pragma unroll
    for (int kk = 0; kk < 4; ++kk) {
      #pragma unroll
      for (int di = 0; di < 4; ++di) {
        float a = TRANSA ? av[kk].f[di] : av[di].f[kk];
        #pragma unroll
        for (int dj = 0; dj < 4; ++dj) {
          float bb = TRANSB ? bv[dj].f[kk] : bv[kk].f[dj];
          acc[di][dj] += a * bb;
        }
      }
    }
  }
  #pragma unroll
  for (int di = 0; di < 4; ++di) {
    if (MODE == 0 && (LDD & 3) == 0) {
      F4 o;
      #pragma unroll
      for (int dj = 0; dj < 4; ++dj) o.f[dj] = acc[di][dj];
      *(float4*)(D + (i0+di)*LDD + j0) = o.v;
    } else {
      #pragma unroll
      for (int dj = 0; dj < 4; ++dj) {
        float v = acc[di][dj];
        if (MODE == 1) v = ADD[(i0+di)*ldadd + j0+dj] + v;
        if (MODE == 2) v = ADD[(i0+di)*ldadd + j0+dj] - v;
        if (MODE == 3) v = v + (((i0+di) == (j0+dj)) ? 1.f : 0.f);
        D[(i0+di)*LDD + j0+dj] = v;
      }
    }
  }
  __syncthreads();
}

// two INDEPENDENT matmuls in one barrier region
template<int TA1,int TB1,int MO1,int LD1, int TA2,int TB2,int MO2,int LD2>
__device__ __forceinline__ void mm2(
    float* __restrict__ D1, const float* __restrict__ A1, int lda1,
    const float* __restrict__ B1, int ldb1, const float* __restrict__ AD1, int ldad1,
    float* __restrict__ D2, const float* __restrict__ A2, int lda2,
    const float* __restrict__ B2, int ldb2, const float* __restrict__ AD2, int ldad2)
{
  const int tid = threadIdx.x;
  const int i0 = (tid >> 4) << 2, j0 = (tid & 15) << 2;
  float acc1[4][4] = {}, acc2[4][4] = {};
  for (int k0 = 0; k0 < NN; k0 += 4) {
    F4 av1[4], bv1[4], av2[4], bv2[4];
    #pragma unroll
    for (int u = 0; u < 4; ++u) {
      bv1[u].v = TB1 ? *(const float4*)(B1 + (j0+u)*ldb1 + k0)
                     : *(const float4*)(B1 + (k0+u)*ldb1 + j0);
      av1[u].v = TA1 ? *(const float4*)(A1 + (k0+u)*lda1 + i0)
                     : *(const float4*)(A1 + (i0+u)*lda1 + k0);
      bv2[u].v = TB2 ? *(const float4*)(B2 + (j0+u)*ldb2 + k0)
                     : *(const float4*)(B2 + (k0+u)*ldb2 + j0);
      av2[u].v = TA2 ? *(const float4*)(A2 + (k0+u)*lda2 + i0)
                     : *(const float4*)(A2 + (i0+u)*lda2 + k0);
    }
    #pragma unroll
    for (int kk = 0; kk < 4; ++kk) {
      #pragma unroll
      for (int di = 0; di < 4; ++di) {
        float a1 = TA1 ? av1[kk].f[di] : av1[di].f[kk];
        float a2 = TA2 ? av2[kk].f[di] : av2[di].f[kk];
        #pragma unroll
        for (int dj = 0; dj < 4; ++dj) {
          acc1[di][dj] += a1 * (TB1 ? bv1[dj].f[kk] : bv1[kk].f[dj]);
          acc2[di][dj] += a2 * (TB2 ? bv2[dj].f[kk] : bv2[kk].f[dj]);
        }
      }
    }
  }
  #pragma unroll
  for (int di = 0; di < 4; ++di) {
    if (MO1 == 0 && (LD1 & 3) == 0) {
      F4 o;
      #pragma unroll
      for (int dj = 0; dj < 4; ++dj) o.f[dj] = acc1[di][dj];
      *(float4*)(D1 + (i0+di)*LD1 + j0) = o.v;
    } else {
      #pragma unroll
      for (int dj = 0; dj < 4; ++dj) {
        float v = acc1[di][dj];
        if (MO1 == 1) v = AD1[(i0+di)*ldad1 + j0+dj] + v;
        if (MO1 == 2) v = AD1[(i0+di)*ldad1 + j0+dj] - v;
        D1[(i0+di)*LD1 + j0+dj] = v;
      }
    }
  }
  #pragma unroll
  for (int di = 0; di < 4; ++di) {
    if (MO2 == 0 && (LD2 & 3) == 0) {
      F4 o;
      #pragma unroll
      for (int dj = 0; dj < 4; ++dj) o.f[dj] = acc2[di][dj];
      *(float4*)(D2 + (i0+di)*LD2 + j0) = o.v;
    } else {
      #pragma unroll
      for (int dj = 0; dj < 4; ++dj) {
        float v = acc2[di][dj];
        if (MO2 == 1) v = AD2[(i0+di)*ldad2 + j0+dj] + v;
        if (MO2 == 2) v = AD2[(i0+di)*ldad2 + j0+dj] - v;
        D2[(i0+di)*LD2 + j0+dj] = v;
      }
    }
  }
  __syncthreads();
}

// specialized pair: D1(+dup D1b) = A1^T A1 [+AD1 if MO1==1]; D2 = AD2 - A2^T A2.
// All LDS operands stride LDW; AD2 stride runtime. Per-cell FP order == mm2.
template<int MO1>
__device__ __forceinline__ void mm2j(
    float* __restrict__ D1, float* __restrict__ D1b,
    const float* __restrict__ A1, const float* __restrict__ AD1,
    float* __restrict__ D2, const float* __restrict__ A2,
    const float* __restrict__ AD2, int ldad2)
{
  const int tid = threadIdx.x;
  const int i0 = (tid >> 4) << 2, j0 = (tid & 15) << 2;
  float acc1[4][4] = {}, acc2[4][4] = {};
  for (int k0 = 0; k0 < NN; k0 += 4) {
    F4 av1[4], bv1[4], av2[4], bv2[4];
    #pragma unroll
    for (int u = 0; u < 4; ++u) {
      bv1[u].v = *(const float4*)(A1 + (k0+u)*LDW + j0);
      av1[u].v = *(const float4*)(A1 + (k0+u)*LDW + i0);
      bv2[u].v = *(const float4*)(A2 + (k0+u)*LDW + j0);
      av2[u].v = *(const float4*)(A2 + (k0+u)*LDW + i0);
    }
    #pragma unroll
    for (int kk = 0; kk < 4; ++kk) {
      #pragma unroll
      for (int di = 0; di < 4; ++di) {
        float a1 = av1[kk].f[di];
        float a2 = av2[kk].f[di];
        #pragma unroll
        for (int dj = 0; dj < 4; ++dj) {
          acc1[di][dj] += a1 * bv1[kk].f[dj];
          acc2[di][dj] += a2 * bv2[kk].f[dj];
        }
      }
    }
  }
  #pragma unroll
  for (int di = 0; di < 4; ++di) {
    #pragma unroll
    for (int dj = 0; dj < 4; ++dj) {
      float v = acc1[di][dj];
      if (MO1 == 1) v = AD1[(i0+di)*LDW + j0+dj] + v;
      D1[(i0+di)*LDW + j0+dj] = v;
      D1b[(i0+di)*LDW + j0+dj] = v;
      float w = AD2[(i0+di)*ldad2 + j0+dj] - acc2[di][dj];
      D2[(i0+di)*LDW + j0+dj] = w;
    }
  }
  __syncthreads();
}

// panel-16 Cholesky in stride-LDW buffer (256 threads). upper zeroed.
template<bool WANTLOG>
__device__ __forceinline__ void chol68(float* __restrict__ Sm, float* part, float* invd) {
  const int tid = threadIdx.x;
  const int lane = tid & 63;
  #pragma unroll
  for (int p = 0; p < 4; ++p) {
    const int j0 = p * 16;
    if (p > 0) {
      const int i = tid & 63;
      const int jq = (tid >> 6) * 4;
      float acc[4] = {0.f, 0.f, 0.f, 0.f};
      for (int kb = 0; kb < j0; kb += 4) {
        F4 av; av.v = *(const float4*)(Sm + i*LDW + kb);
        #pragma unroll
        for (int q = 0; q < 4; ++q) {
          F4 bv; bv.v = *(const float4*)(Sm + (j0 + jq + q)*LDW + kb);
          acc[q] += av.f[0]*bv.f[0] + av.f[1]*bv.f[1] + av.f[2]*bv.f[2] + av.f[3]*bv.f[3];
        }
      }
      #pragma unroll
      for (int q = 0; q < 4; ++q)
        Sm[i*LDW + j0 + jq + q] -= acc[q];
      __syncthreads();
    }
    if (tid < 64) {
      float t[16];
      F4 tv;
      #pragma unroll
      for (int q4 = 0; q4 < 4; ++q4) {
        tv.v = *(const float4*)(Sm + lane*LDW + j0 + 4*q4);
        t[4*q4] = tv.f[0]; t[4*q4+1] = tv.f[1]; t[4*q4+2] = tv.f[2]; t[4*q4+3] = tv.f[3];
      }
      #pragma unroll
      for (int jj = 0; jj < 16; ++jj) {
        float acc = t[jj];
        #pragma unroll
        for (int kk = 0; kk < jj; ++kk)
          acc -= __shfl(t[kk], j0 + jj, 64) * t[kk];
        float piv = __shfl(acc, j0 + jj, 64);
        float sq = sqrtf(fmaxf(piv, 1e-30f));
        float inv = 1.0f / sq;
        if (lane == j0 + jj) {
          t[jj] = sq;
          invd[j0 + jj] = inv;
          if (WANTLOG) part[j0 + jj] = logf(sq);
        } else {
          t[jj] = (lane > j0 + jj) ? acc * inv : 0.f;
        }
      }
      #pragma unroll
      for (int q4 = 0; q4 < 4; ++q4) {
        tv.f[0] = t[4*q4]; tv.f[1] = t[4*q4+1]; tv.f[2] = t[4*q4+2]; tv.f[3] = t[4*q4+3];
        *(float4*)(Sm + lane*LDW + j0 + 4*q4) = tv.v;
      }
    }
    __syncthreads();
  }
}

// forward triangular solve DST <- L^-1 op(SRC); TR=1 reads SRC transposed.
template<int TR>
__device__ __forceinline__ void tri_fwd_ld(const float* __restrict__ L,
                                           const float* __restrict__ invd,
                                           const float* __restrict__ SRC, int lds,
                                           float* __restrict__ DST, int ldd) {
  const int col = threadIdx.x >> 2, p = threadIdx.x & 3;
  const int gbase = (threadIdx.x & 63) & ~3;
  float xr[16];
  #pragma unroll
  for (int u = 0; u < 16; ++u)
    xr[u] = TR ? SRC[col*lds + (4*u+p)] : SRC[(4*u+p)*lds + col];
  #pragma unroll
  for (int i = 0; i < NN; ++i) {
    const int idx = i >> 2, ow = i & 3;
    float yi = xr[idx] * invd[i];
    yi = __shfl(yi, gbase + ow, 64);
    if (p == ow) xr[idx] = yi;
    else if (p > ow) xr[idx] -= L[(4*idx+p)*LDW + i] * yi;
    #pragma unroll
    for (int u = idx+1; u < 16; ++u)
      xr[u] -= L[(4*u+p)*LDW + i] * yi;
  }
  #pragma unroll
  for (int u = 0; u < 16; ++u) DST[(4*u+p)*ldd + col] = xr[u];
  __syncthreads();
}

// TWO independent forward solves in one barrier region
template<int TR1,int TR2>
__device__ __forceinline__ void tri_fwd2(
    const float* __restrict__ L1, const float* __restrict__ ivd1,
    const float* __restrict__ S1, int lds1, float* __restrict__ D1, int ldd1,
    const float* __restrict__ L2, const float* __restrict__ ivd2,
    const float* __restrict__ S2, int lds2, float* __restrict__ D2, int ldd2)
{
  const int col = threadIdx.x >> 2, p = threadIdx.x & 3;
  const int gbase = (threadIdx.x & 63) & ~3;
  float xr[16], xs[16];
  #pragma unroll
  for (int u = 0; u < 16; ++u) {
    xr[u] = TR1 ? S1[col*lds1 + (4*u+p)] : S1[(4*u+p)*lds1 + col];
    xs[u] = TR2 ? S2[col*lds2 + (4*u+p)] : S2[(4*u+p)*lds2 + col];
  }
  #pragma unroll
  for (int i = 0; i < NN; ++i) {
    const int idx = i >> 2, ow = i & 3;
    float yi = xr[idx] * ivd1[i];
    yi = __shfl(yi, gbase + ow, 64);
    float zi = xs[idx] * ivd2[i];
    zi = __shfl(zi, gbase + ow, 64);
    if (p == ow) xr[idx] = yi;
    else if (p > ow) xr[idx] -= L1[(4*idx+p)*LDW + i] * yi;
    if (p == ow) xs[idx] = zi;
    else if (p > ow) xs[idx] -= L2[(4*idx+p)*LDW + i] * zi;
    #pragma unroll
    for (int u = idx+1; u < 16; ++u) {
      xr[u] -= L1[(4*u+p)*LDW + i] * yi;
      xs[u] -= L2[(4*u+p)*LDW + i] * zi;
    }
  }
  #pragma unroll
  for (int u = 0; u < 16; ++u) {
    D1[(4*u+p)*ldd1 + col] = xr[u];
    D2[(4*u+p)*ldd2 + col] = xs[u];
  }
  __syncthreads();
}

// backward triangular solve DST <- L^-T SRC
__device__ __forceinline__ void tri_bwd_ld(const float* __restrict__ L,
                                           const float* __restrict__ invd,
                                           const float* __restrict__ SRC, int lds,
                                           float* __restrict__ DST, int ldd) {
  const int col = threadIdx.x >> 2, p = threadIdx.x & 3;
  const int gbase = (threadIdx.x & 63) & ~3;
  float xr[16];
  #pragma unroll
  for (int u = 0; u < 16; ++u) xr[u] = SRC[(4*u+p)*lds + col];
  #pragma unroll
  for (int i = NN-1; i >= 0; --i) {
    const int idx = i >> 2, ow = i & 3;
    float zi = xr[idx] * invd[i];
    zi = __shfl(zi, gbase + ow, 64);
    if (p == ow) xr[idx] = zi;
    else if (p < ow) xr[idx] -= L[i*LDW + 4*idx+p] * zi;
    #pragma unroll
    for (int u = 0; u < idx; ++u)
      xr[u] -= L[i*LDW + 4*u+p] * zi;
  }
  #pragma unroll
  for (int u = 0; u < 16; ++u) DST[(4*u+p)*ldd + col] = xr[u];
  __syncthreads();
}

// one forward + one backward solve (same L), interleaved
__device__ __forceinline__ void tri_fb2(
    const float* __restrict__ L, const float* __restrict__ ivd,
    const float* __restrict__ Sf, int ldsf, float* __restrict__ Df, int lddf,
    const float* __restrict__ Sb, int ldsb, float* __restrict__ Db, int lddb)
{
  const int col = threadIdx.x >> 2, p = threadIdx.x & 3;
  const int gbase = (threadIdx.x & 63) & ~3;
  float xf[16], xb[16];
  #pragma unroll
  for (int u = 0; u < 16; ++u) {
    xf[u] = Sf[(4*u+p)*ldsf + col];
    xb[u] = Sb[(4*u+p)*ldsb + col];
  }
  #pragma unroll
  for (int k = 0; k < NN; ++k) {
    {
      const int i = k, idx = i >> 2, ow = i & 3;
      float yi = xf[idx] * ivd[i];
      yi = __shfl(yi, gbase + ow, 64);
      if (p == ow) xf[idx] = yi;
      else if (p > ow) xf[idx] -= L[(4*idx+p)*LDW + i] * yi;
      #pragma unroll
      for (int u = idx+1; u < 16; ++u)
        xf[u] -= L[(4*u+p)*LDW + i] * yi;
    }
    {
      const int i = NN-1-k, idx = i >> 2, ow = i & 3;
      float zi = xb[idx] * ivd[i];
      zi = __shfl(zi, gbase + ow, 64);
      if (p == ow) xb[idx] = zi;
      else if (p < ow) xb[idx] -= L[i*LDW + 4*idx+p] * zi;
      #pragma unroll
      for (int u = 0; u < idx; ++u)
        xb[u] -= L[i*LDW + 4*u+p] * zi;
    }
  }
  #pragma unroll
  for (int u = 0; u < 16; ++u) {
    Df[(4*u+p)*lddf + col] = xf[u];
    Db[(4*u+p)*lddb + col] = xb[u];
  }
  __syncthreads();
}

// two-sided triangular solve: DST <- L^-T L^-1 SRC
__device__ __forceinline__ void tri_solve2(const float* __restrict__ L,
                                           const float* __restrict__ invd,
                                           const float* __restrict__ SRC,
                                           float* __restrict__ DST) {
  const int col = threadIdx.x >> 2, p = threadIdx.x & 3;
  const int gbase = (threadIdx.x & 63) & ~3;
  float xr[16];
  #pragma unroll
  for (int u = 0; u < 16; ++u) xr[u] = SRC[(4*u+p)*LDW + col];
  #pragma unroll
  for (int i = 0; i < NN; ++i) {
    const int idx = i >> 2, ow = i & 3;
    float yi = xr[idx] * invd[i];
    yi = __shfl(yi, gbase + ow, 64);
    if (p == ow) xr[idx] = yi;
    else if (p > ow) xr[idx] -= L[(4*idx+p)*LDW + i] * yi;
    #pragma unroll
    for (int u = idx+1; u < 16; ++u)
      xr[u] -= L[(4*u+p)*LDW + i] * yi;
  }
  #pragma unroll
  for (int i = NN-1; i >= 0; --i) {
    const int idx = i >> 2, ow = i & 3;
    float zi = xr[idx] * invd[i];
    zi = __shfl(zi, gbase + ow, 64);
    if (p == ow) xr[idx] = zi;
    else if (p < ow) xr[idx] -= L[i*LDW + 4*idx+p] * zi;
    #pragma unroll
    for (int u = 0; u < idx; ++u)
      xr[u] -= L[i*LDW + 4*u+p] * zi;
  }
  #pragma unroll
  for (int u = 0; u < 16; ++u) DST[(4*u+p)*LDW + col] = xr[u];
  __syncthreads();
}

// TWO independent two-sided solves (same L), in-place, stride LDW
__device__ __forceinline__ void tri_s2x2(const float* __restrict__ L,
                                         const float* __restrict__ invd,
                                         float* __restrict__ X1,
                                         float* __restrict__ X2) {
  const int col = threadIdx.x >> 2, p = threadIdx.x & 3;
  const int gbase = (threadIdx.x & 63) & ~3;
  float xr[16], xs[16];
  #pragma unroll
  for (int u = 0; u < 16; ++u) {
    xr[u] = X1[(4*u+p)*LDW + col];
    xs[u] = X2[(4*u+p)*LDW + col];
  }
  #pragma unroll
  for (int i = 0; i < NN; ++i) {
    const int idx = i >> 2, ow = i & 3;
    float yi = xr[idx] * invd[i];
    yi = __shfl(yi, gbase + ow, 64);
    float zi = xs[idx] * invd[i];
    zi = __shfl(zi, gbase + ow, 64);
    if (p == ow) xr[idx] = yi;
    else if (p > ow) xr[idx] -= L[(4*idx+p)*LDW + i] * yi;
    if (p == ow) xs[idx] = zi;
    else if (p > ow) xs[idx] -= L[(4*idx+p)*LDW + i] * zi;
    #pragma unroll
    for (int u = idx+1; u < 16; ++u) {
      xr[u] -= L[(4*u+p)*LDW + i] * yi;
      xs[u] -= L[(4*u+p)*LDW + i] * zi;
    }
  }
  #pragma unroll
  for (int i = NN-1; i >= 0; --i) {
    const int idx = i >> 2, ow = i & 3;
    float yi = xr[idx] * invd[i];
    yi = __shfl(yi, gbase + ow, 64);
    float zi = xs[idx] * invd[i];
    zi = __shfl(zi, gbase + ow, 64);
    if (p == ow) xr[idx] = yi;
    else if (p < ow) xr[idx] -= L[i*LDW + 4*idx+p] * yi;
    if (p == ow) xs[idx] = zi;
    else if (p < ow) xs[idx] -= L[i*LDW + 4*idx+p] * zi;
    #pragma unroll
    for (int u = 0; u < idx; ++u) {
      xr[u] -= L[i*LDW + 4*u+p] * yi;
      xs[u] -= L[i*LDW + 4*u+p] * zi;
    }
  }
  #pragma unroll
  for (int u = 0; u < 16; ++u) {
    X1[(4*u+p)*LDW + col] = xr[u];
    X2[(4*u+p)*LDW + col] = xs[u];
  }
  __syncthreads();
}

// y(64) = M1*x1 + M2*x2 + addv. 256 threads. y may alias x1/x2/addv.
__device__ __forceinline__ void matvec2(float* __restrict__ y,
    const float* __restrict__ M1, const float* __restrict__ x1,
    const float* __restrict__ M2, const float* __restrict__ x2,
    const float* __restrict__ addv, float* __restrict__ red) {
  const int r = threadIdx.x & 63, p = threadIdx.x >> 6;
  const int kb = p*16;
  float s = 0.f;
  #pragma unroll
  for (int q = 0; q < 4; ++q) {
    F4 mv; mv.v = *(const float4*)(M1 + r*NN + kb + q*4);
    s += mv.f[0]*x1[kb+q*4] + mv.f[1]*x1[kb+q*4+1] + mv.f[2]*x1[kb+q*4+2] + mv.f[3]*x1[kb+q*4+3];
    F4 nv; nv.v = *(const float4*)(M2 + r*NN + kb + q*4);
    s += nv.f[0]*x2[kb+q*4] + nv.f[1]*x2[kb+q*4+1] + nv.f[2]*x2[kb+q*4+2] + nv.f[3]*x2[kb+q*4+3];
  }
  red[p*64 + r] = s;
  __syncthreads();
  if (threadIdx.x < 64) {
    float t = red[r] + red[64+r] + red[128+r] + red[192+r];
    y[r] = t + addv[r];
  }
  __syncthreads();
}

// y = Mg*x + addv (nullable). 256 threads.
__device__ __forceinline__ void matvec256(float* __restrict__ y, const float* __restrict__ Mg,
    const float* __restrict__ x, const float* __restrict__ addv, float* __restrict__ red) {
  const int r = threadIdx.x & 63, p = threadIdx.x >> 6;
  const int kb = p*16;
  float s = 0.f;
  #pragma unroll
  for (int q = 0; q < 4; ++q) {
    F4 mv; mv.v = *(const float4*)(Mg + r*NN + kb + q*4);
    s += mv.f[0]*x[kb+q*4] + mv.f[1]*x[kb+q*4+1] + mv.f[2]*x[kb+q*4+2] + mv.f[3]*x[kb+q*4+3];
  }
  red[p*64 + r] = s;
  __syncthreads();
  if (threadIdx.x < 64) {
    float t = red[r] + red[64+r] + red[128+r] + red[192+r];
    y[r] = t + (addv ? addv[r] : 0.f);
  }
  __syncthreads();
}

// ---------- kernels ----------

__global__ __launch_bounds__(256) void k0(KP P) {
  __shared__ __align__(16) float W0[LDW*NN];
  const int tid = threadIdx.x;
  for (int e = tid; e < 4096; e += 256) {
    int r = e>>6, cc = e&63;
    P.AT[e] = P.A[cc*64+r];
    P.HT[e] = P.H[cc*64+r];
  }
  if (tid < 64) {
    float s = 0.f;
    for (int k = 0; k < 64; ++k) s += P.H[tid*64+k]*P.b[k];
    P.Hb[tid] = s;
  }
  __syncthreads();
  mm<0,0,0,LDW>(W0, P.H, NN, P.A, NN, nullptr, 0);   // HA = H*A
  l2g(P.HA, W0);
}

// kA: leaf + fP0 + 5 doublings (E^2..E^32), pointer-swapped, dual-store, +I fused
__global__ __launch_bounds__(256) void kA(KP P) {
  __shared__ __align__(16) float LA[LDW*NN], LC[LDW*NN], LJ[LDW*NN], LL[LDW*NN];
  __shared__ __align__(16) float W0[LDW*NN], W1[LDW*NN], W2[LDW*NN], W3[LDW*NN], W4[LDW*NN];
  __shared__ float part[64], iv1[64], iv2[64];
  float *pA = LA, *pC = LC, *pJ = LJ, *pL = LL;
  float *s0 = W0, *s1 = W1, *s2 = W2, *s3 = W3, *s4 = W4;
  // ---- leaf ----
  mm2<0,0,0,LDW, 0,0,0,LDW>(s0, P.H,NN, P.Q,NN, nullptr,0,
                            s2, P.H,NN, P.P0,NN, nullptr,0);      // T ; HP0
  mm2<0,1,1,LDW, 0,1,1,LDW>(s1, s0,LDW, P.H,NN, P.R,NN,
                            s3, s2,LDW, P.H,NN, P.R,NN);          // St ; S0
  chol68<false>(s1, part, iv1);
  chol68<false>(s3, part, iv2);
  tri_fwd2<0,0>(s1, iv1, P.HA,NN, s4,LDW,
                s3, iv2, s2,LDW,  s2,LDW);                         // U ; U0
  mm2j<0>(pJ, pL, s4, nullptr, s3, s2, P.P0, NN);                  // Jt(dual) ; fP0->s3
  l2g(P.fP, s3);
  chol68<false>(pL, part, iv2);                                    // Lt
  tri_fb2(s1, iv1, s0,LDW, s3,LDW,  s4,LDW, s4,LDW);               // V->s3 ; X->s4
  mm2<1,0,2,LDW, 1,0,2,LDW>(pA, s0,LDW, s4,LDW, P.A,NN,
                            pC, s3,LDW, s3,LDW, P.Q,NN);           // At ; Ct
  l2g3(P.EA, pA, P.EC, pC, P.EL, pL);
  // ---- doublings ----
  for (int j = 0; j < 5 && (2 << j) <= P.N0cap - 1; ++j) {
    mm2<0,0,0,LDW, 1,0,0,LDW>(s0, pC,LDW, pL,LDW, nullptr,0,
                              s2, pL,LDW, pA,LDW, nullptr,0);      // Pm ; T1
    mm<1,0,3,LDW>(s1, pL,LDW, s0,LDW, nullptr,0);                  // W = L^T Pm + I
    chol68<false>(s1, part, iv1);                                   // Lw
    tri_fwd2<0,1>(s1, iv1, s2,LDW, s2,LDW,
                  s1, iv1, s0,LDW, s3,LDW);                         // T2f ; T5
    mm2j<1>(pJ, pL, s2, pJ, s4, s3, pC, LDW);                       // Jn(dual) ; ZC->s4
    chol68<false>(pL, part, iv2);                                   // Ln
    tri_bwd_ld(s1, iv1, s2,LDW, s2,LDW);                            // T2
    mm<0,0,2,LDW>(s3, s0,LDW, s2,LDW, pA,LDW);                      // ZA
    mm2<0,0,0,LDW, 0,0,0,LDW>(s2, pA,LDW, s3,LDW, nullptr,0,
                              s0, pA,LDW, s4,LDW, nullptr,0);       // An->s2 ; T7->s0
    mm<0,1,1,LDW>(pC, s0,LDW, pA,LDW, pC,LDW);                      // Cn in place
    { float* tmp = pA; pA = s2; s2 = tmp; }
    l2g3(P.EA+(size_t)(j+1)*4096, pA, P.EC+(size_t)(j+1)*4096, pC,
         P.EL+(size_t)(j+1)*4096, pL);
  }
}

// block t: fP_t via greedy decomposition; also pP_{t+1}
__global__ __launch_bounds__(256) void kB(KP P) {
  __shared__ __align__(16) float Wc[LDW*NN], W0[LDW*NN], W1[LDW*NN], W2[LDW*NN];
  __shared__ float part[64], ivw[64];
  const int t = blockIdx.x;
  if (t == 0) {
    for (int e = threadIdx.x*4; e < 4096; e += 1024)
      *(float4*)(P.pP + e) = *(const float4*)(P.P0 + e);
    __syncthreads();
    mm<0,0,0,LDW>(W1, P.A, NN, P.fP, NN, nullptr, 0);
    mm<0,0,1,LDW>(W0, W1, LDW, P.AT, NN, P.Q, NN);
    l2g(P.pP + 4096, W0);
    return;
  }
  g2l(Wc, P.fP);
  int rem = t;
  for (int j = 5; j >= 0; --j) {
    const int pw = 1 << j;
    if (j > 0 && pw > P.N0cap - 1) continue;
    while (rem >= pw) {
      const float* Ag = P.EA + j*4096;
      const float* Cg = P.EC + j*4096;
      const float* Lg = P.EL + j*4096;
      mm<0,0,0,LDW>(W0, Wc, LDW, Lg, NN, nullptr, 0);     // Pm = C L
      mm<1,0,3,LDW>(W1, Lg, NN, W0, LDW, nullptr, 0);     // W = L^T Pm + I
      chol68<false>(W1, part, ivw);
      tri_fwd_ld<1>(W1, ivw, W0, LDW, W2, LDW);           // T5
      mm<1,0,2,LDW>(W1, W2, LDW, W2, LDW, Wc, LDW);       // ZC
      mm<0,0,0,LDW>(W0, Ag, NN, W1, LDW, nullptr, 0);     // T7
      mm<0,1,1,LDW>(Wc, W0, LDW, Ag, NN, Cg, NN);         // C'
      rem -= pw;
    }
  }
  l2g(P.fP + (size_t)t*4096, Wc);
  mm<0,0,0,LDW>(W0, P.A, NN, Wc, LDW, nullptr, 0);
  mm<0,0,1,LDW>(W1, W0, LDW, P.AT, NN, P.Q, NN);
  l2g(P.pP + (size_t)(t+1)*4096, W1);
}

__global__ __launch_bounds__(256) void kC(KP P) {
  __shared__ float red[16];
  const int t = blockIdx.x;
  const float* cur = P.fP + (size_t)t*4096;
  const float* prv = P.fP + (size_t)(t > 0 ? t-1 : 0)*4096;
  float a = 0.f, d = 0.f;
  for (int e = threadIdx.x*4; e < 4096; e += 1024) {
    F4 v, pv; v.v = *(const float4*)(cur + e); pv.v = *(const float4*)(prv + e);
    #pragma unroll
    for (int q = 0; q < 4; ++q) {
      a = fmaxf(a, fabsf(v.f[q]));
      d = fmaxf(d, fabsf(v.f[q] - pv.f[q]));
    }
  }
  redpair(a, d, red);
  if (threadIdx.x == 0) { P.astat[t] = a; P.dstat[t] = (t > 0) ? d : 0.f; }
}

__global__ __launch_bounds__(256) void kN(KP P) {
  __shared__ float as_[N0MAX], ds_[N0MAX];
  const int cap = P.N0cap;
  for (int i = threadIdx.x; i < cap; i += 256) { as_[i] = P.astat[i]; ds_[i] = P.dstat[i]; }
  __syncthreads();
  if (threadIdx.x == 0) {
    float mabs = 1e-20f, dref = 1e30f;
    int tref = 0, N0 = cap;
    bool conv = false;
    for (int t = 0; t < cap; ++t) {
      mabs = fmaxf(mabs, as_[t]);
      if (t > 0) {
        float d = ds_[t];
        if (d <= EPS_HARD*mabs) { N0 = t+1; conv = true; }
        if (d < STALL_IMP*dref) { dref = d; tref = t; }
        else if (t - tref >= STALL_WIN && t >= 12 && d < EPS_GATE*mabs) { N0 = t+1; conv = true; }
      }
      if (conv) break;
    }
    P.meta[0] = N0; P.metaF[1] = mabs;
  }
}

// merged: blocks 0..cap-1 = per-t derived quantities; last block = steady-state part A
__global__ __launch_bounds__(256) void k1x(KP P) {
  __shared__ __align__(16) float W0[LDW*NN], W1[LDW*NN], W2[LDW*NN], CH[LDW*NN];
  __shared__ float part[64], invd[64];
  const int tid = threadIdx.x;
  const int N0 = P.meta[0];
  if ((int)blockIdx.x == (int)gridDim.x - 1) {
    const float* fPssG = P.fP + (size_t)(N0-1)*4096;
    g2l(CH, fPssG);
    mm<0,0,0,LDW>(W1, P.A, NN, CH, LDW, nullptr, 0);
    mm<0,0,1,LDW>(W0, W1, LDW, P.AT, NN, P.Q, NN);            // pPss
    l2g(P.pPss, W0);
    mm<0,0,0,LDW>(W1, P.H, NN, W0, LDW, nullptr, 0);          // HP
    mm<0,0,1,LDW>(CH, W1, LDW, P.HT, NN, P.R, NN);            // S
    chol68<true>(CH, part, invd);
    if (tid == 0) { float s=0.f; for (int j=0;j<64;++j) s += part[j]; P.metaF[0] = s; }
    set_id(W0);
    tri_s2x2(CH, invd, W1, W0);                               // X ; Sinv
    l2g_T(P.Kss, W1);
    if (tid < 64) {
      float s = P.b[tid];
      for (int k = 0; k < 64; ++k) s -= W1[k*LDW + tid]*P.Hb[k];
      P.uss[tid] = s;
    }
    __syncthreads();
    l2g(P.Sinvss, W0);
    mm<1,0,2,LDW>(W0, W1, LDW, P.HA, NN, P.A, NN);            // F_ss
    l2g(P.Fss, W0);
    mm<0,0,0,LDW>(W1, P.A, NN, fPssG, NN, nullptr, 0);        // AF
    g2l(CH, P.pPss);
    chol68<false>(CH, part, invd);
    tri_solve2(CH, invd, W1, W1);                             // X2 = Css^T
    l2g(P.CsTss, W1);
    l2g_T(P.Css, W1);
    mm<1,0,0,LDW>(W2, W1, LDW, P.A, NN, nullptr, 0);          // Css*A
    store_id_sub(P.Dmss, W2);
    if (tid < 64) {
      float s = 0.f;
      for (int k = 0; k < 64; ++k) s += W1[k*LDW + tid]*P.b[k];
      P.dvnss[tid] = -s;
    }
    return;
  }
  const int t = blockIdx.x;
  if (t >= N0) return;
  mm<0,0,0,LDW>(W1, P.H, NN, P.pP + (size_t)t*4096, NN, nullptr, 0);
  mm<0,0,1,LDW>(CH, W1, LDW, P.HT, NN, P.R, NN);
  chol68<true>(CH, part, invd);
  if (tid == 0) { float s=0.f; for (int j=0;j<64;++j) s += part[j]; P.ld_pref[t] = s; }
  set_id(W0);
  tri_s2x2(CH, invd, W1, W0);
  l2g_T(P.Kp + (size_t)t*4096, W1);
  if (tid < 64) {
    float s = P.b[tid];
    for (int k = 0; k < 64; ++k) s -= W1[k*LDW + tid]*P.Hb[k];
    P.u_pref[t*64 + tid] = s;
  }
  __syncthreads();
  l2g(P.Sinvp + (size_t)t*4096, W0);
  mm<1,0,2,LDW>(W0, W1, LDW, P.HA, NN, P.A, NN);
  l2g(P.Fp + (size_t)t*4096, W0);
  mm<0,0,0,LDW>(W1, P.A, NN, P.fP + (size_t)t*4096, NN, nullptr, 0);
  g2l(CH, P.pP + (size_t)(t+1)*4096);
  chol68<false>(CH, part, invd);
  tri_solve2(CH, invd, W1, W1);                               // X2 = C_t^T
  l2g(P.CsTp + (size_t)t*4096, W1);
  l2g_T(P.Cp + (size_t)t*4096, W1);
  mm<1,0,0,LDW>(W0, W1, LDW, P.A, NN, nullptr, 0);            // C_t*A
  store_id_sub(P.Dmp + (size_t)t*4096, W0);
  if (tid < 64) {
    float s = 0.f;
    for (int k = 0; k < 64; ++k) s += W1[k*LDW + tid]*P.b[k];
    P.dvnp[t*64 + tid] = -s;
  }
}

// mega0: bid0 = k2b ; bid1,2 = k1y ; bid 3..3+NC-1 = k2a ; bid 3+NC.. = k1cI
__global__ __launch_bounds__(256) void mega0(KP P) {
  __shared__ __align__(16) float W0[LDW*NN], W1[LDW*NN], W2[LDW*NN], W3[LDW*NN], W4[LDW*NN], CH[LDW*NN];
  __shared__ float xv[64], ty[64], hp[64], red[256];
  const int tid = threadIdx.x;
  const int bid = blockIdx.x;
  const int N0 = P.meta[0];
  const int PB = (N0 + LCH - 1)/LCH;
  if (bid == 0) {
    const int PE = PB*LCH;
    if (tid < 64) xv[tid] = P.pm0[tid];
    __syncthreads();
    matvec256(hp, P.H, xv, nullptr, red);
    if (tid < 64) ty[tid] = P.Y[tid] - hp[tid] - P.c[tid];
    __syncthreads();
    matvec256(xv, P.Kp, ty, xv, red);
    if (tid < 64) P.fm[tid] = xv[tid];
    __syncthreads();
    for (int t = 1; t < PE; ++t) {
      const float* Kt = (t < N0) ? P.Kp + (size_t)t*4096 : P.Kss;
      const float* Ft = (t < N0) ? P.Fp + (size_t)t*4096 : P.Fss;
      const float* ut = (t < N0) ? P.u_pref + t*64 : P.uss;
      if (tid < 64) ty[tid] = P.Y[(size_t)t*64+tid] - P.c[tid];
      __syncthreads();
      matvec2(xv, Ft, xv, Kt, ty, ut, red);
      if (tid < 64) P.fm[(size_t)t*64+tid] = xv[tid];
      __syncthreads();
    }
    if (tid < 64) P.scanF0[(size_t)PB*64 + tid] = xv[tid];
  } else if (bid <= 2) {
    const float* fPssG = P.fP + (size_t)(N0-1)*4096;
    if (bid == 1) {
      mm2<0,0,0,LDW, 0,0,0,LDW>(W1, P.Css,NN, P.Css,NN, nullptr,0,
                                W4, P.Fss,NN, P.Fss,NN, nullptr,0);   // C2 ; F2
      l2g(P.Pw2, W1);
      mm2<0,0,0,LDW, 0,0,0,LDW>(W2, W1,LDW, W1,LDW, nullptr,0,
                                W3, W4,LDW, W4,LDW, nullptr,0);       // C4 ; F4
      l2g(P.Pw4, W2);
      mm2<0,0,0,LDW, 0,0,0,LDW>(W0, W2,LDW, W2,LDW, nullptr,0,
                                W4, W3,LDW, W3,LDW, nullptr,0);       // C8 ; F8
      l2g(P.Pw8, W0);
      mm2<0,0,0,LDW, 0,0,0,LDW>(W1, W0,LDW, W0,LDW, nullptr,0,
                                W3, W4,LDW, W4,LDW, nullptr,0);       // C16 ; F16
      l2g(P.Pw16, W1);
      mm2<0,0,0,LDW, 0,0,0,LDW>(W2, W1,LDW, W1,LDW, nullptr,0,
                                W4, W3,LDW, W3,LDW, nullptr,0);       // C32 ; F32
      l2g2(P.Cpow32, W2, P.Fpow, W4);
      mm2<0,0,0,LDW, 0,0,0,LDW>(W0, W2,LDW, W2,LDW, nullptr,0,
                                W3, W4,LDW, W4,LDW, nullptr,0);       // C64 ; F64
      l2g2(P.Pw64, W0, P.FpwHi, W3);
      mm2<0,0,0,LDW, 0,0,0,LDW>(W1, W0,LDW, W0,LDW, nullptr,0,
                                W4, W3,LDW, W3,LDW, nullptr,0);       // C128 ; F128
      l2g2(P.Pw128, W1, P.FpwHi + 4096, W4);
      mm2<0,0,0,LDW, 0,0,0,LDW>(W2, W1,LDW, W1,LDW, nullptr,0,
                                W3, W4,LDW, W4,LDW, nullptr,0);       // C256 ; F256
      l2g2(P.CpwHi, W2, P.FpwHi + 2*4096, W3);
      mm2<0,0,0,LDW, 0,0,0,LDW>(W0, W2,LDW, W2,LDW, nullptr,0,
                                W4, W3,LDW, W3,LDW, nullptr,0);       // C512 ; F512
      l2g2(P.CpwHi + 4096, W0, P.FpwHi + 3*4096, W4);
      mm2<0,0,0,LDW, 0,0,0,LDW>(W1, W0,LDW, W0,LDW, nullptr,0,
                                W3, W4,LDW, W4,LDW, nullptr,0);       // C1024 ; F1024
      l2g2(P.CpwHi + 2*4096, W1, P.FpwHi + 4*4096, W3);
      mm2<0,0,0,LDW, 0,0,0,LDW>(W2, W1,LDW, W1,LDW, nullptr,0,
                                W4, W3,LDW, W3,LDW, nullptr,0);       // C2048 ; F2048
      l2g2(P.CpwHi + 3*4096, W2, P.FpwHi + 5*4096, W4);
      mm<0,0,0,LDW>(W0, P.Pw16, NN, P.Pw8, NN, nullptr, 0);           // C24
      mm<0,0,0,LDW>(W1, W0, LDW, P.Pw4, NN, nullptr, 0);              // C28
      mm<0,0,0,LDW>(W2, W1, LDW, P.Pw2, NN, nullptr, 0);              // C30
      mm<0,0,0,LDW>(W0, W2, LDW, P.Css, NN, nullptr, 0);              // C31
      l2g(P.Cpow31, W0);
    } else {
      g2l(W1, P.Css);
      g2l(W2, P.CsTss);
      g2l(W0, P.pPss);
      mm<0,0,0,LDW>(CH, W1, LDW, W0, LDW, nullptr, 0);                // C*pPss
      mm<0,0,2,LDW>(W0, CH, LDW, W2, LDW, fPssG, NN);                 // X = fPss - (C pPss) C'
      float *m1 = W1, *m2 = W2, *t1 = W3, *t2 = W4;
      for (int it = 0; it < 7; ++it) {
        mm2<0,0,0,LDW, 0,0,0,LDW>(CH, m1,LDW, W0,LDW, nullptr,0,
                                  t1, m1,LDW, m1,LDW, nullptr,0);     // M*X ; M^2
        mm2<0,0,1,LDW, 0,0,0,LDW>(W0, CH,LDW, m2,LDW, W0,LDW,
                                  t2, m2,LDW, m2,LDW, nullptr,0);     // X += (MX)M' ; M'^2
        float* tmp = m1; m1 = t1; t1 = tmp;
        tmp = m2; m2 = t2; t2 = tmp;
      }
      l2g(P.sPss, W0);
      rsub_store(P.E0g, fPssG, W0);
    }
  } else if (bid < 3 + P.NC) {
    const int c = bid - 3;
    if (c < PB) return;
    if (tid < 64) xv[tid] = 0.f;
    __syncthreads();
    for (int s = 0; s < LCH; ++s) {
      int t = c*LCH + s;
      if (tid < 64) ty[tid] = P.Y[(size_t)t*64+tid] - P.c[tid];
      __syncthreads();
      matvec2(xv, P.Fss, xv, P.Kss, ty, P.uss, red);
    }
    if (tid < 64) P.scanF0[(size_t)(c+1)*64 + tid] = xv[tid];
  } else {
    const int t = bid - 3 - P.NC;
    if (t >= N0) return;
    const float* Cg = P.Cp + (size_t)t*4096;
    for (int e = tid*4; e < 4096; e += 1024)
      *(float4*)(P.scM0 + (size_t)t*4096 + e) = *(const float4*)(Cg + e);
    mm<0,0,0,LDW>(W1, Cg, NN, P.pP + (size_t)(t+1)*4096, NN, nullptr, 0);
    mm<0,0,2,NN>(P.scG0 + (size_t)t*4096, W1, LDW,
                 P.CsTp + (size_t)t*4096, NN, P.fP + (size_t)t*4096, NN);
  }
}

// megaL (level d < 7): bid<cap = k1cL level d ; rest = k2s level d
__global__ __launch_bounds__(256) void megaL(KP P, int d) {
  __shared__ __align__(16) float W1[LDW*NN];
  __shared__ float xv[64];
  const int tid = threadIdx.x;
  const int bid = blockIdx.x;
  const int cap = P.N0cap;
  const int N0 = P.meta[0];
  if (bid < cap) {
    const int t = bid;
    if (t >= N0) return;
    const int step = 1 << d, sidx = d & 1;
    const float* Msrc = sidx ? P.scM1 : P.scM0;
    const float* Gsrc = sidx ? P.scG1 : P.scG0;
    float* Mdst = sidx ? P.scM0 : P.scM1;
    float* Gdst = sidx ? P.scG0 : P.scG1;
    const int s = t + step;
    if (s >= N0) {
      for (int e = tid*4; e < 4096; e += 1024) {
        *(float4*)(Mdst + (size_t)t*4096 + e) = *(const float4*)(Msrc + (size_t)t*4096 + e);
        *(float4*)(Gdst + (size_t)t*4096 + e) = *(const float4*)(Gsrc + (size_t)t*4096 + e);
      }
      return;
    }
    const float* Mt = Msrc + (size_t)t*4096;
    mm2<0,0,0,LDW, 0,0,0,NN>(W1, Mt,NN, Gsrc + (size_t)s*4096,NN, nullptr,0,
                             Mdst + (size_t)t*4096, Mt,NN, Msrc + (size_t)s*4096,NN, nullptr,0);
    mm<0,1,1,NN>(Gdst + (size_t)t*4096, W1, LDW, Mt, NN, Gsrc + (size_t)t*4096, NN);
  } else {
    const int c = bid - cap;
    const int PB = (N0 + LCH - 1)/LCH;
    if (c < PB) return;
    const int sidx = d & 1;
    const float* src = sidx ? P.scanF1 : P.scanF0;
    float* dst = sidx ? P.scanF0 : P.scanF1;
    const int off = 1 << d;
    const int r = tid;
    if (c - off >= PB) {
      if (r < 64) xv[r] = src[(size_t)(c-off)*64 + r];
      __syncthreads();
      if (r < 64) {
        const float* M = (d == 0) ? P.Fpow : P.FpwHi + (size_t)(d-1)*4096;
        const float* Mr = M + r*64;
        float s = src[(size_t)c*64 + r];
        for (int k = 0; k < 64; k += 4)
          s += Mr[k]*xv[k] + Mr[k+1]*xv[k+1] + Mr[k+2]*xv[k+2] + Mr[k+3]*xv[k+3];
        dst[(size_t)c*64 + r] = s;
      }
    } else {
      if (r < 64) dst[(size_t)c*64 + r] = src[(size_t)c*64 + r];
    }
  }
}

// megaL7: bid<NC = k2c (steady-chunk replay) ; rest = k1cL level 7
__global__ __launch_bounds__(256) void megaL7(KP P) {
  __shared__ __align__(16) float W1[LDW*NN];
  __shared__ float xv[64], ty[64], red[256];
  const int tid = threadIdx.x;
  const int bid = blockIdx.x;
  const int N0 = P.meta[0];
  const int PB = (N0 + LCH - 1)/LCH;
  if (bid < P.NC) {
    const int c = bid;
    if (c < PB) return;
    if (tid < 64) xv[tid] = P.scanF1[(size_t)c*64 + tid];
    __syncthreads();
    for (int s = 0; s < LCH; ++s) {
      int t = c*LCH + s;
      if (tid < 64) ty[tid] = P.Y[(size_t)t*64+tid] - P.c[tid];
      __syncthreads();
      matvec2(xv, P.Fss, xv, P.Kss, ty, P.uss, red);
      if (tid < 64) P.fm[(size_t)t*64+tid] = xv[tid];
      __syncthreads();
    }
  } else {
    const int t = bid - P.NC;
    if (t >= N0) return;
    const int step = 128, sidx = 1;
    const float* Msrc = sidx ? P.scM1 : P.scM0;
    const float* Gsrc = sidx ? P.scG1 : P.scG0;
    float* Mdst = sidx ? P.scM0 : P.scM1;
    float* Gdst = sidx ? P.scG0 : P.scG1;
    const int s = t + step;
    if (s >= N0) {
      for (int e = tid*4; e < 4096; e += 1024) {
        *(float4*)(Mdst + (size_t)t*4096 + e) = *(const float4*)(Msrc + (size_t)t*4096 + e);
        *(float4*)(Gdst + (size_t)t*4096 + e) = *(const float4*)(Gsrc + (size_t)t*4096 + e);
      }
      return;
    }
    const float* Mt = Msrc + (size_t)t*4096;
    mm2<0,0,0,LDW, 0,0,0,NN>(W1, Mt,NN, Gsrc + (size_t)s*4096,NN, nullptr,0,
                             Mdst + (size_t)t*4096, Mt,NN, Msrc + (size_t)s*4096,NN, nullptr,0);
    mm<0,1,1,NN>(Gdst + (size_t)t*4096, W1, LDW, Mt, NN, Gsrc + (size_t)t*4096, NN);
  }
}

// mega2: bid<NC = k3a ; +T = kTail ; +cap = k1cF ; +T = k5 ; +PEcap = sv-scan init
__global__ __launch_bounds__(256) void mega2(KP P) {
  __shared__ __align__(16) float W0[LDW*NN], W1[LDW*NN], W2[LDW*NN];
  __shared__ float sv[64], fmv[64], red[256];
  const int tid = threadIdx.x;
  const int bid = blockIdx.x;
  const int NC = P.NC, cap = P.N0cap, T = P.T;
  const int N0 = P.meta[0];
  const int PB = (N0 + LCH - 1)/LCH;
  if (bid < NC) {
    // ---- k3a ----
    const int c = bid;
    if (c < PB) return;
    if (tid < 64) sv[tid] = 0.f;
    __syncthreads();
    int hi = (c == NC-1) ? T-2 : c*LCH + LCH - 1;
    for (int t = hi; t >= c*LCH; --t) {
      if (tid < 64) fmv[tid] = P.fm[(size_t)t*64+tid];
      __syncthreads();
      matvec2(sv, P.Css, sv, P.Dmss, fmv, P.dvnss, red);
    }
    if (c == NC-1) {
      if (tid < 64) fmv[tid] = P.fm[(size_t)(T-1)*64 + tid];
      __syncthreads();
      matvec256(sv, P.Cpow31, fmv, sv, red);
    }
    if (tid < 64) P.scanB0[(size_t)c*64 + tid] = sv[tid];
  } else if (bid < NC + T) {
    // ---- kTail ----
    const int t = bid - NC;
    if (t < N0) return;
    float* dst = P.out_cov + (size_t)t*4096;
    if (t < T - N1CAP) {
      for (int e = tid*4; e < 4096; e += 1024)
        *(float4*)(dst+e) = *(const float4*)(P.sPss + e);
      return;
    }
    const int k = T - 1 - t;
    if (k == 0) {
      const float* src = P.fP + (size_t)(N0-1)*4096;
      for (int e = tid*4; e < 4096; e += 1024)
        *(float4*)(dst+e) = *(const float4*)(src+e);
      return;
    }
    const float* pw[8] = {P.Css, P.Pw2, P.Pw4, P.Pw8, P.Pw16, P.Cpow32, P.Pw64, P.Pw128};
    int b = __ffs(k) - 1;
    g2l(W1, pw[b]);
    float* cur = W1; float* oth = W0;
    for (int j = b+1; j < 8; ++j) {
      if ((k >> j) & 1) {
        mm<0,0,0,LDW>(oth, pw[j], NN, cur, LDW, nullptr, 0);
        float* tmp = cur; cur = oth; oth = tmp;
      }
    }
    mm<0,0,0,LDW>(W2, cur, LDW, P.E0g, NN, nullptr, 0);
    mm<0,1,1,LDW>(oth, W2, LDW, cur, LDW, P.sPss, NN);
    l2g(dst, oth);
  } else if (bid < NC + T + cap) {
    // ---- k1cF ----
    const int t = bid - NC - T;
    if (t >= N0) return;
    const float* Mt = P.scM0 + (size_t)t*4096;
    mm<0,0,0,LDW>(W1, Mt, NN, P.sPss, NN, nullptr, 0);
    mm<0,1,1,NN>(P.out_cov + (size_t)t*4096, W1, LDW, Mt, NN,
                 P.scG0 + (size_t)t*4096, NN);
  } else if (bid < NC + T + cap + T) {
    // ---- k5 ----
    const int t = bid - NC - T - cap;
    const int r = tid;
    if (t == 0) {
      if (r < 64) fmv[r] = P.pm0[r];
      __syncthreads();
    } else {
      if (r < 64) sv[r] = P.fm[(size_t)(t-1)*64 + r];
      __syncthreads();
      if (r < 64) {
        float s = P.b[r];
        const float* Ar = P.A + r*64;
        for (int k = 0; k < 64; k += 4)
          s += Ar[k]*sv[k] + Ar[k+1]*sv[k+1] + Ar[k+2]*sv[k+2] + Ar[k+3]*sv[k+3];
        fmv[r] = s;
      }
      __syncthreads();
    }
    if (r < 64) {
      float rr = P.Y[(size_t)t*64 + r] - P.c[r];
      const float* Hr = P.H + r*64;
      for (int k = 0; k < 64; ++k) rr -= Hr[k]*fmv[k];
      sv[r] = rr;
    }
    __syncthreads();
    if (r < 64) {
      const float* Sv = ((t < N0) ? P.Sinvp + (size_t)t*4096 : P.Sinvss) + r*64;
      float wv = 0.f;
      for (int k = 0; k < 64; ++k) wv += Sv[k]*sv[k];
      float qq = sv[r]*wv;
      #pragma unroll
      for (int off = 32; off > 0; off >>= 1) qq += __shfl_xor(qq, off, 64);
      if (r == 0) {
        float ldt = (t < N0) ? P.ld_pref[t] : P.metaF[0];
        P.llbuf[t] = -58.8120661250990555 - (double)ldt - 0.5*(double)qq;
      }
    }
  } else {
    // ---- sv-scan init: element t = (C~_t, w_t) into scM1/scG1 ----
    const int t = bid - NC - T - cap - T;
    const int PE = PB*LCH;
    if (t >= PE) return;
    const float* Ct  = (t < N0) ? P.Cp  + (size_t)t*4096 : P.Css;
    const float* Dmt = (t < N0) ? P.Dmp + (size_t)t*4096 : P.Dmss;
    const float* dvt = (t < N0) ? P.dvnp + t*64 : P.dvnss;
    for (int e = tid*4; e < 4096; e += 1024)
      *(float4*)(P.scM1 + (size_t)t*4096 + e) = *(const float4*)(Ct + e);
    matvec256(P.scG1 + (size_t)t*4096, Dmt, P.fm + (size_t)t*64, dvt, red);
  }
}

// mega3s (level d = 0..7): bid<PEcap = sv-scan level ; rest = backward chunk-carry (d<7)
__global__ __launch_bounds__(256) void mega3s(KP P, int d) {
  __shared__ float xv[64], red[256];
  const int tid = threadIdx.x;
  const int bid = blockIdx.x;
  const int N0 = P.meta[0];
  const int PB = (N0 + LCH - 1)/LCH;
  const int PE = PB*LCH;
  const int PEcap = ((P.N0cap + 31)/32)*32;
  if (bid < PEcap) {
    const int t = bid;
    if (t >= PE) return;
    const float* Msrc = (d % 2 == 0) ? P.scM1 : P.scM0;
    const float* Vsrc = (d % 2 == 0) ? P.scG1 : P.scG0;
    float* Mdst = (d % 2 == 0) ? P.scM0 : P.scM1;
    float* Vdst = (d % 2 == 0) ? P.scG0 : P.scG1;
    const int s = t + (1 << d);
    if (s >= PE) {
      for (int e = tid*4; e < 4096; e += 1024)
        *(float4*)(Mdst + (size_t)t*4096 + e) = *(const float4*)(Msrc + (size_t)t*4096 + e);
      if (tid < 64) Vdst[(size_t)t*4096 + tid] = Vsrc[(size_t)t*4096 + tid];
      return;
    }
    // M' = M_t * M_s ; v' = M_t * v_s + v_t
    mm<0,0,0,NN>(Mdst + (size_t)t*4096, Msrc + (size_t)t*4096, NN,
                 Msrc + (size_t)s*4096, NN, nullptr, 0);
    matvec256(Vdst + (size_t)t*4096, Msrc + (size_t)t*4096,
              Vsrc + (size_t)s*4096, Vsrc + (size_t)t*4096, red);
  } else {
    if (d >= 7) return;
    const int c = bid - PEcap;
    if (c < PB || c >= P.NC) return;
    const int sidx = d & 1;
    const float* src = sidx ? P.scanB1 : P.scanB0;
    float* dst = sidx ? P.scanB0 : P.scanB1;
    const int off = 1 << d;
    if (c + off <= P.NC - 1) {
      if (tid < 64) xv[tid] = src[(size_t)(c+off)*64 + tid];
      __syncthreads();
      if (tid < 64) {
        const float* M;
        if (d == 0) M = P.Cpow32;
        else if (d == 1) M = P.Pw64;
        else if (d == 2) M = P.Pw128;
        else M = P.CpwHi + (size_t)(d-3)*4096;
        const float* Mr = M + tid*64;
        float s = src[(size_t)c*64 + tid];
        for (int k = 0; k < 64; k += 4)
          s += Mr[k]*xv[k] + Mr[k+1]*xv[k+1] + Mr[k+2]*xv[k+2] + Mr[k+3]*xv[k+3];
        dst[(size_t)c*64 + tid] = s;
      }
    } else {
      if (tid < 64) dst[(size_t)c*64 + tid] = src[(size_t)c*64 + tid];
    }
  }
}

// mega3: bid<NC = k3c ; next PEcap = parallel prefix apply ; last = k6
__global__ __launch_bounds__(256) void mega3(KP P) {
  __shared__ float sv[64], fmv[64], red[256];
  __shared__ double rd[256];
  const int tid = threadIdx.x;
  const int bid = blockIdx.x;
  const int N0 = P.meta[0];
  const int PB = (N0 + LCH - 1)/LCH;
  const int PEcap = ((P.N0cap + 31)/32)*32;
  if (bid < P.NC) {
    // ---- k3c ----
    const int c = bid;
    if (c < PB) return;
    if (tid < 64) {
      sv[tid] = (c == P.NC-1) ? P.fm[(size_t)(P.T-1)*64+tid]
                              : P.scanB1[(size_t)(c+1)*64 + tid];
    }
    __syncthreads();
    int hi = (c == P.NC-1) ? P.T-2 : c*LCH + LCH - 1;
    for (int t = hi; t >= c*LCH; --t) {
      if (tid < 64) fmv[tid] = P.fm[(size_t)t*64+tid];
      __syncthreads();
      matvec2(sv, P.Css, sv, P.Dmss, fmv, P.dvnss, red);
      if (tid < 64) P.out_mean[(size_t)t*64+tid] = sv[tid];
      __syncthreads();
    }
  } else if (bid < P.NC + PEcap) {
    // ---- prefix apply: out_mean[t] = M_t * seed + v_t  (seed = scanB1[PB]) ----
    const int t = bid - P.NC;
    const int PE = PB*LCH;
    if (t == 0) {
      if (tid < 64) P.out_mean[(size_t)(P.T-1)*64+tid] = P.fm[(size_t)(P.T-1)*64+tid];
      __syncthreads();
    }
    if (t >= PE) return;
    // sv-scan final parity: 8 levels end in scM1/scG1
    matvec256(P.out_mean + (size_t)t*64, P.scM1 + (size_t)t*4096,
              P.scanB1 + (size_t)PB*64, P.scG1 + (size_t)t*4096, red);
  } else {
    // ---- k6 ----
    double s = 0.0;
    for (int t = tid; t < P.T; t += 256) s += P.llbuf[t];
    rd[tid] = s; __syncthreads();
    #pragma unroll
    for (int off = 128; off > 0; off >>= 1) {
      if (tid < off) rd[tid] += rd[tid + off];
      __syncthreads();
    }
    if (tid == 0) P.out_ll[0] = (float)rd[0];
  }
}

// ---------- host ----------

extern "C" void kernel_launch(void* const* d_in, const int* in_sizes, int n_in,
                              void* d_out, int out_size, void* d_ws, size_t ws_size,
                              hipStream_t stream) {
  (void)n_in; (void)out_size;
  KP P;
  P.Y   = (const float*)d_in[0];
  P.A   = (const float*)d_in[1];
  P.b   = (const float*)d_in[2];
  P.Q   = (const float*)d_in[3];
  P.H   = (const float*)d_in[4];
  P.c   = (const float*)d_in[5];
  P.R   = (const float*)d_in[6];
  P.pm0 = (const float*)d_in[7];
  P.P0  = (const float*)d_in[8];
  const int T = in_sizes[0] / 64;
  const int NC = T / LCH;
  P.T = T; P.NC = NC;

  float* out = (float*)d_out;
  P.out_mean = out;
  P.out_cov  = out + (size_t)T*64;
  P.out_ll   = out + (size_t)T*64 + (size_t)T*4096;

  float* w = (float*)d_ws;
  size_t off = 0;
  auto alloc = [&](size_t n) { float* p = w + off; off += n; return p; };
  P.meta   = (int*)alloc(8);
  P.metaF  = alloc(8);
  P.llbuf  = (double*)alloc((size_t)2*T);
  P.fm     = alloc((size_t)T*64);
  P.AT = alloc(4096); P.HT = alloc(4096); P.HA = alloc(4096); P.Hb = alloc(64);
  P.Fss = alloc(4096); P.Kss = alloc(4096); P.Sinvss = alloc(4096);
  P.Css = alloc(4096); P.CsTss = alloc(4096); P.pPss = alloc(4096); P.sPss = alloc(4096);
  P.Fpow = alloc(4096); P.Cpow32 = alloc(4096); P.Cpow31 = alloc(4096); P.uss = alloc(64);
  P.Pw2 = alloc(4096); P.Pw4 = alloc(4096); P.Pw8 = alloc(4096); P.Pw16 = alloc(4096);
  P.Pw64 = alloc(4096); P.Pw128 = alloc(4096);
  P.FpwHi = alloc((size_t)6*4096); P.CpwHi = alloc((size_t)4*4096);
  P.Dmss = alloc(4096); P.dvnss = alloc(64);
  P.scanF0 = alloc((size_t)(NC+1)*64); P.scanF1 = alloc((size_t)(NC+1)*64);
  P.scanB0 = alloc((size_t)NC*64); P.scanB1 = alloc((size_t)NC*64);
  P.E0g = alloc(4096);
  P.EA = alloc((size_t)8*4096); P.EC = alloc((size_t)8*4096);
  P.EJ = alloc((size_t)8*4096); P.EL = alloc((size_t)8*4096);
  P.astat = alloc(256); P.dstat = alloc(256);
  size_t fixed = off;
  size_t per_t = 12*4096 + 128 + 1;
  size_t total_f = ws_size / 4;
  long long avail = (long long)total_f - (long long)fixed - 4096 - 64
                  - 4LL*32*4096;   // scan-buffer growth to cap+32 slots
  int cap = (avail > 0) ? (int)(avail / (long long)per_t) : 8;
  if (cap > N0MAX) cap = N0MAX;
  if (cap < 8) cap = 8;
  P.N0cap = cap;
  const int PEcap = ((cap + 31)/32)*32;
  P.ld_pref = alloc(cap);
  P.u_pref  = alloc((size_t)cap*64);
  P.dvnp    = alloc((size_t)cap*64);
  P.fP    = alloc((size_t)cap*4096);
  P.pP    = alloc((size_t)(cap+1)*4096);
  P.Kp    = alloc((size_t)cap*4096);
  P.Sinvp = alloc((size_t)cap*4096);
  P.Fp    = alloc((size_t)cap*4096);
  P.Cp    = alloc((size_t)cap*4096);
  P.CsTp  = alloc((size_t)cap*4096);
  P.Dmp   = alloc((size_t)cap*4096);
  P.scM0  = alloc((size_t)(cap+32)*4096);
  P.scM1  = alloc((size_t)(cap+32)*4096);
  P.scG0  = alloc((size_t)(cap+32)*4096);
  P.scG1  = alloc((size_t)(cap+32)*4096);

  k0<<<1, 256, 0, stream>>>(P);
  kA<<<1, 256, 0, stream>>>(P);
  kB<<<cap, 256, 0, stream>>>(P);
  kC<<<cap, 256, 0, stream>>>(P);
  kN<<<1, 256, 0, stream>>>(P);
  k1x<<<cap+1, 256, 0, stream>>>(P);
  mega0<<<3 + NC + cap, 256, 0, stream>>>(P);           // k2b ∥ k1y ∥ k2a ∥ k1cI
  for (int d = 0; d < 7; ++d)
    megaL<<<cap + NC, 256, 0, stream>>>(P, d);          // k1cL[d] ∥ k2s[d]
  megaL7<<<NC + cap, 256, 0, stream>>>(P);              // k2c ∥ k1cL[7]
  mega2<<<NC + T + cap + T + PEcap, 256, 0, stream>>>(P); // k3a ∥ kTail ∥ k1cF ∥ k5 ∥ sv-init
  for (int d = 0; d < 8; ++d)
    mega3s<<<PEcap + NC, 256, 0, stream>>>(P, d);       // sv-scan level ∥ bwd chunk-carry
  mega3<<<NC + PEcap + 1, 256, 0, stream>>>(P);         // k3c ∥ prefix-apply ∥ k6
}